// Round 5
// baseline (578.965 us; speedup 1.0000x reference)
//
#include <hip/hip_runtime.h>
#include <hip/hip_bf16.h>
#include <hip/hip_cooperative_groups.h>

namespace cg = cooperative_groups;

// GraphFourierLayer: B=32, N=4096, C_IN=128, C_OUT=128, M=256
#define BB 32
#define NN 4096
#define CI 128
#define CO 128
#define MM 256
#define KS 8           // K-split factor for stage 1 (N=4096 -> 8 chunks of 512)

typedef __hip_bfloat16 bf16;
typedef __attribute__((ext_vector_type(8))) short bf16x8;
typedef __attribute__((ext_vector_type(4))) float f32x4;

__device__ inline void gl_lds16(const void* g, void* l) {
    __builtin_amdgcn_global_load_lds(
        (const __attribute__((address_space(1))) void*)g,
        (__attribute__((address_space(3))) void*)l, 16, 0, 0);
}

// ===========================================================================
// MEGA-KERNEL: whole pipeline in one cooperative launch.
// 512 blocks x 256 threads, 64 KB LDS/block -> 2 blocks/CU co-resident.
// Phases separated by device-fence + grid.sync(). All phase bodies are the
// verified multi-kernel bodies re-indexed onto (blk 0..511, t 0..255).
// Purpose: (a) eliminate 4 kernel boundaries (gap hypothesis), (b) make the
// whole pipeline ONE >40us dispatch so rocprof top-5 finally shows our
// counters (MfmaUtil/FETCH/LDS conflicts) instead of only fillBuffer.
// ===========================================================================
__global__ __launch_bounds__(256, 2) void k_all(const float* __restrict__ x,
                                                const float* __restrict__ U,
                                                const float* __restrict__ W,
                                                float* __restrict__ out,
                                                bf16* __restrict__ part,
                                                bf16* __restrict__ Ut,
                                                bf16* __restrict__ Un,
                                                bf16* __restrict__ osT,
                                                bf16* __restrict__ Wt) {
    cg::grid_group grid = cg::this_grid();
    const int blk = blockIdx.x;        // 0..511
    const int t   = threadIdx.x;       // 0..255
    __shared__ __align__(16) char smem[64 * 1024];

    // ---------------- P0: preps (cvtU on blocks 0..255, wt on 256..511) ----
    if (blk < 256) {
        // U fp32 [N][M] -> Un bf16 [N][M] and Ut bf16 [M][N]; 64x64 tiles
        const int n0 = (blk & 63) * 64;
        const int m0 = (blk >> 6) * 64;
        float (*tile)[65] = (float(*)[65])smem;
        #pragma unroll
        for (int i = 0; i < 16; ++i) {
            int lin = t + i * 256;
            int r = lin >> 6, c = lin & 63;
            float v = U[(n0 + r) * MM + m0 + c];
            tile[r][c] = v;
            Un[(n0 + r) * MM + m0 + c] = __float2bfloat16(v);
        }
        __syncthreads();
        #pragma unroll
        for (int pass = 0; pass < 2; ++pass) {
            int no = t & 7;
            int m  = (t >> 3) + pass * 32;
            bf16 tmp[8];
            #pragma unroll
            for (int j = 0; j < 8; ++j) tmp[j] = __float2bfloat16(tile[no * 8 + j][m]);
            *(bf16x8*)&Ut[(long)(m0 + m) * NN + n0 + no * 8] = *(bf16x8*)tmp;
        }
    } else {
        // W fp32 [C][O][M] -> Wt bf16 [M][C][O]; each block does 4 c-slices
        const int q  = blk - 256;
        const int m0 = (q & 3) * 64;
        const int o0 = ((q >> 2) & 1) * 64;
        const int cb = q >> 3;                 // 0..31
        float (*tile)[65] = (float(*)[65])smem;
        for (int ci = 0; ci < 4; ++ci) {
            const int c = cb * 4 + ci;
            #pragma unroll
            for (int pass = 0; pass < 4; ++pass) {
                int r  = (t >> 4) + pass * 16;
                int m4 = (t & 15) * 4;
                float4 v = *(const float4*)&W[((long)c * CO + o0 + r) * MM + m0 + m4];
                tile[r][m4 + 0] = v.x; tile[r][m4 + 1] = v.y;
                tile[r][m4 + 2] = v.z; tile[r][m4 + 3] = v.w;
            }
            __syncthreads();
            #pragma unroll
            for (int pass = 0; pass < 2; ++pass) {
                int oo = t & 7;
                int m  = (t >> 3) + pass * 32;
                bf16 tmp[8];
                #pragma unroll
                for (int j = 0; j < 8; ++j) tmp[j] = __float2bfloat16(tile[oo * 8 + j][m]);
                *(bf16x8*)&Wt[((long)(m0 + m) * CI + c) * CO + o0 + oo * 8] = *(bf16x8*)tmp;
            }
            __syncthreads();   // protect tile before next ci overwrites it
        }
    }
    __threadfence();
    grid.sync();

    // ---------------- P1: gemm1 fused (x transpose+convert in-kernel) ------
    // part[ks][b][m][c] = sum_n Ut[m][n] * x[b][n][c]; 128m x 128c tiles,
    // 4 waves, acc[4][4]. Blocks (ks 8) x (mt 2) x (b 32) = 512. The mt pair
    // for one (ks,b) lands on the same XCD (blk and blk+8) -> x tile L2-shared.
    {
        const int ks = blk & 7;
        const int mt = (blk >> 3) & 1;
        const int b  = blk >> 4;
        const int m0 = mt * 128;
        bf16*  As = (bf16*)smem;                   // [2][128*32]
        bf16*  Bs = (bf16*)(smem + 16 * 1024);     // [2][128*32]
        float* Xf = (float*)(smem + 32 * 1024);    // [2][32*128]
        const int lane = t & 63, wave = t >> 6;
        const int wm = wave >> 1, wn = wave & 1;
        const int fr = lane & 15, kg = (lane >> 4) * 8;
        f32x4 acc[4][4] = {};
        const long xrow  = (long)b * NN;
        const int  kbase = ks * 512;

        auto STAGE1 = [&](int buf, int kt) {
            const int k0 = kbase + kt * 32;
            #pragma unroll
            for (int i = 0; i < 2; ++i) {
                int lin = t + i * 256;
                int r = lin >> 2, kk = (lin & 3) * 8;
                gl_lds16(&Ut[(long)(m0 + r) * NN + k0 + kk], &As[buf * 4096 + lin * 8]);
            }
            #pragma unroll
            for (int i = 0; i < 4; ++i) {
                int lin = t + i * 256;
                int r = lin >> 5, c4 = (lin & 31) * 4;
                gl_lds16(&x[(xrow + k0 + r) * CI + c4], &Xf[buf * 4096 + lin * 4]);
            }
        };

        STAGE1(0, 0);
        __syncthreads();
        for (int kt = 0; kt < 16; ++kt) {
            const int cur = kt & 1;
            {   // transpose+convert Xf[cur] [32n][128c] -> Bs[cur] [128c][32n]
                const int c = t & 127;
                #pragma unroll
                for (int pass = 0; pass < 2; ++pass) {
                    int no = (t >> 7) + pass * 2;       // 0..3
                    bf16 tmp[8];
                    #pragma unroll
                    for (int j = 0; j < 8; ++j)
                        tmp[j] = __float2bfloat16(Xf[cur * 4096 + (no * 8 + j) * CI + c]);
                    *(bf16x8*)&Bs[cur * 4096 + c * 32 + no * 8] = *(bf16x8*)tmp;
                }
            }
            __syncthreads();                     // Bs[cur] visible
            if (kt + 1 < 16) STAGE1(cur ^ 1, kt + 1);   // loads fly under MFMA
            bf16x8 a[4], bfr[4];
            #pragma unroll
            for (int i = 0; i < 4; ++i)
                a[i] = *(const bf16x8*)&As[cur * 4096 + (wm * 64 + i * 16 + fr) * 32 + kg];
            #pragma unroll
            for (int j = 0; j < 4; ++j)
                bfr[j] = *(const bf16x8*)&Bs[cur * 4096 + (wn * 64 + j * 16 + fr) * 32 + kg];
            #pragma unroll
            for (int i = 0; i < 4; ++i)
                #pragma unroll
                for (int j = 0; j < 4; ++j)
                    acc[i][j] = __builtin_amdgcn_mfma_f32_16x16x32_bf16(a[i], bfr[j], acc[i][j], 0, 0, 0);
            __syncthreads();                     // drain loads + protect bufs
        }
        const int quad = (lane >> 4) * 4;
        const long pbase = ((long)ks * BB + b) * MM * CI;
        #pragma unroll
        for (int i = 0; i < 4; ++i) {
            #pragma unroll
            for (int j = 0; j < 4; ++j) {
                int mg = m0 + wm * 64 + i * 16 + quad;
                int cg = wn * 64 + j * 16 + fr;
                #pragma unroll
                for (int r = 0; r < 4; ++r)
                    part[pbase + (long)(mg + r) * CI + cg] = __float2bfloat16(acc[i][j][r]);
            }
        }
    }
    __threadfence();
    grid.sync();

    // ---------------- P2: reduce partials + per-mode mix -> osT ------------
    // Baseline (verified) o-half version: blk -> (mode, o-half)
    {
        const int mi = blk >> 1;
        const int m  = (mi & 7) * 32 + (mi >> 3);   // XCD swizzle
        const int o0 = (blk & 1) * 64;
        float* Wl = (float*)smem;                   // [128][64] = 32 KB
        float* xl = (float*)(smem + 32 * 1024);     // [128][36] = 18 KB
        const long wb = (long)m * CI * CO;
        #pragma unroll
        for (int i = 0; i < 4; ++i) {
            int ch = t + i * 256;
            int c = ch >> 3, og = (ch & 7) * 8;
            bf16x8 v = *(const bf16x8*)&Wt[wb + (long)c * CO + o0 + og];
            #pragma unroll
            for (int j = 0; j < 8; ++j) Wl[c * 64 + og + j] = __bfloat162float(((const bf16*)&v)[j]);
        }
        #pragma unroll
        for (int i = 0; i < 2; ++i) {
            int ch = t + i * 256;
            int b2 = ch >> 4, c8 = (ch & 15) * 8;
            float s[8] = {};
            #pragma unroll
            for (int ks = 0; ks < KS; ++ks) {
                bf16x8 v = *(const bf16x8*)&part[(((long)ks * BB + b2) * MM + m) * CI + c8];
                #pragma unroll
                for (int j = 0; j < 8; ++j) s[j] += __bfloat162float(((const bf16*)&v)[j]);
            }
            #pragma unroll
            for (int j = 0; j < 8; ++j) xl[(c8 + j) * 36 + b2] = s[j];
        }
        __syncthreads();
        const int op = t & 63;
        const int bq = t >> 6;
        float acc[8] = {};
        for (int c = 0; c < CI; ++c) {
            float w = Wl[c * 64 + op];
            #pragma unroll
            for (int j = 0; j < 8; ++j)
                acc[j] += xl[c * 36 + bq * 8 + j] * w;
        }
        #pragma unroll
        for (int j = 0; j < 8; ++j)
            osT[((long)(bq * 8 + j) * CO + o0 + op) * MM + m] = __float2bfloat16(acc[j]);
    }
    __threadfence();
    grid.sync();

    // ---------------- P3: gemm3 x2 tiles ----------------------------------
    // out[b][n][o] = sum_m Un[n][m] * osT[b][o][m]; verified single-buffer
    // body; each block does 2 n-tiles for its b (osT[b] stays L2-hot).
    {
        const int b3 = blk >> 4;                    // 0..31
        bf16* As3 = (bf16*)smem;                    // [128*32] = 8 KB
        bf16* Bs3 = (bf16*)(smem + 8 * 1024);       // [128*32] = 8 KB
        const int lane = t & 63, wave = t >> 6;
        const int wm = wave >> 1, wn = wave & 1;
        const int fr = lane & 15, kg = (lane >> 4) * 8;
        const long bbase = (long)b3 * CO * MM;
        for (int rr = 0; rr < 2; ++rr) {
            const int n0 = ((blk & 15) * 2 + rr) * 128;
            f32x4 acc[4][4] = {};
            for (int kt = 0; kt < MM / 32; ++kt) {
                const int k0 = kt * 32;
                #pragma unroll
                for (int i = 0; i < 2; ++i) {
                    int lin = t + i * 256;
                    int r = lin >> 2, kk = (lin & 3) * 8;
                    gl_lds16(&Un[(long)(n0 + r) * MM + k0 + kk], &As3[lin * 8]);
                    gl_lds16(&osT[bbase + (long)r * MM + k0 + kk], &Bs3[lin * 8]);
                }
                __syncthreads();
                bf16x8 a[4], bfr[4];
                #pragma unroll
                for (int i = 0; i < 4; ++i)
                    a[i] = *(const bf16x8*)&As3[(wm * 64 + i * 16 + fr) * 32 + kg];
                #pragma unroll
                for (int j = 0; j < 4; ++j)
                    bfr[j] = *(const bf16x8*)&Bs3[(wn * 64 + j * 16 + fr) * 32 + kg];
                #pragma unroll
                for (int i = 0; i < 4; ++i)
                    #pragma unroll
                    for (int j = 0; j < 4; ++j)
                        acc[i][j] = __builtin_amdgcn_mfma_f32_16x16x32_bf16(a[i], bfr[j], acc[i][j], 0, 0, 0);
                __syncthreads();
            }
            const int quad = (lane >> 4) * 4;
            #pragma unroll
            for (int i = 0; i < 4; ++i) {
                #pragma unroll
                for (int j = 0; j < 4; ++j) {
                    int ng = n0 + wm * 64 + i * 16 + quad;
                    int og = wn * 64 + j * 16 + fr;
                    #pragma unroll
                    for (int r = 0; r < 4; ++r)
                        out[((long)b3 * NN + ng + r) * CO + og] = acc[i][j][r];
                }
            }
        }
    }
}

// ===========================================================================
// FALLBACK multi-kernel path (round-4, passing at 187.5 us) -- used only if
// the cooperative launch is rejected by the runtime/capture.
// ===========================================================================
__global__ __launch_bounds__(256) void k_cvtU(const float* __restrict__ U,
                                              bf16* __restrict__ Un,
                                              bf16* __restrict__ Ut) {
    const int n0 = blockIdx.x * 64;
    const int m0 = blockIdx.y * 64;
    __shared__ float tile[64][65];
    const int t = threadIdx.x;
    #pragma unroll
    for (int i = 0; i < 16; ++i) {
        int lin = t + i * 256;
        int r = lin >> 6, c = lin & 63;
        float v = U[(n0 + r) * MM + m0 + c];
        tile[r][c] = v;
        Un[(n0 + r) * MM + m0 + c] = __float2bfloat16(v);
    }
    __syncthreads();
    #pragma unroll
    for (int pass = 0; pass < 2; ++pass) {
        int no = t & 7;
        int m  = (t >> 3) + pass * 32;
        bf16 tmp[8];
        #pragma unroll
        for (int j = 0; j < 8; ++j) tmp[j] = __float2bfloat16(tile[no * 8 + j][m]);
        *(bf16x8*)&Ut[(long)(m0 + m) * NN + n0 + no * 8] = *(bf16x8*)tmp;
    }
}

__global__ __launch_bounds__(256) void k_wt(const float* __restrict__ W,
                                            bf16* __restrict__ Wt) {
    const int m0 = blockIdx.x * 64;
    const int o0 = blockIdx.y * 64;
    const int c  = blockIdx.z;
    __shared__ float tile[64][65];
    const int t = threadIdx.x;
    #pragma unroll
    for (int pass = 0; pass < 4; ++pass) {
        int r  = (t >> 4) + pass * 16;
        int m4 = (t & 15) * 4;
        float4 v = *(const float4*)&W[((long)c * CO + o0 + r) * MM + m0 + m4];
        tile[r][m4 + 0] = v.x; tile[r][m4 + 1] = v.y;
        tile[r][m4 + 2] = v.z; tile[r][m4 + 3] = v.w;
    }
    __syncthreads();
    #pragma unroll
    for (int pass = 0; pass < 2; ++pass) {
        int oo = t & 7;
        int m  = (t >> 3) + pass * 32;
        bf16 tmp[8];
        #pragma unroll
        for (int j = 0; j < 8; ++j) tmp[j] = __float2bfloat16(tile[oo * 8 + j][m]);
        *(bf16x8*)&Wt[((long)(m0 + m) * CI + c) * CO + o0 + oo * 8] = *(bf16x8*)tmp;
    }
}

__global__ __launch_bounds__(512) void k_gemm1f(const bf16* __restrict__ Ut,
                                                const float* __restrict__ x,
                                                bf16* __restrict__ part) {
    const int ks = blockIdx.x;
    const int b  = blockIdx.y;
    __shared__ __align__(16) bf16  As[2][MM * 32];
    __shared__ __align__(16) bf16  Bs[2][CI * 32];
    __shared__ __align__(16) float Xf[2][32 * CI];
    const int t    = threadIdx.x;
    const int lane = t & 63;
    const int wave = t >> 6;
    const int wm   = wave >> 1, wn = wave & 1;
    const int fr   = lane & 15;
    const int kg   = (lane >> 4) * 8;
    f32x4 acc[4][4] = {};
    const long xrow  = (long)b * NN;
    const int  kbase = ks * 512;

    auto STAGE = [&](int buf, int kt) {
        const int k0 = kbase + kt * 32;
        #pragma unroll
        for (int i = 0; i < 2; ++i) {
            int lin = t + i * 512;
            {
                int r = lin >> 2, kk = (lin & 3) * 8;
                gl_lds16(&Ut[(long)r * NN + k0 + kk], &As[buf][lin * 8]);
            }
            {
                int r = lin >> 5, c4 = (lin & 31) * 4;
                gl_lds16(&x[(xrow + k0 + r) * CI + c4], &Xf[buf][lin * 4]);
            }
        }
    };

    const int NT = 512 / 32;
    STAGE(0, 0);
    __syncthreads();
    #pragma unroll
    for (int kt = 0; kt < NT; ++kt) {
        const int cur = kt & 1;
        {
            const int c  = t & 127;
            const int nh = t >> 7;
            bf16 tmp[8];
            #pragma unroll
            for (int j = 0; j < 8; ++j)
                tmp[j] = __float2bfloat16(Xf[cur][(nh * 8 + j) * CI + c]);
            *(bf16x8*)&Bs[cur][c * 32 + nh * 8] = *(bf16x8*)tmp;
        }
        __syncthreads();
        if (kt + 1 < NT) STAGE(cur ^ 1, kt + 1);
        bf16x8 a[4], bfr[4];
        #pragma unroll
        for (int i = 0; i < 4; ++i)
            a[i] = *(const bf16x8*)&As[cur][(wm * 64 + i * 16 + fr) * 32 + kg];
        #pragma unroll
        for (int j = 0; j < 4; ++j)
            bfr[j] = *(const bf16x8*)&Bs[cur][(wn * 64 + j * 16 + fr) * 32 + kg];
        #pragma unroll
        for (int i = 0; i < 4; ++i)
            #pragma unroll
            for (int j = 0; j < 4; ++j)
                acc[i][j] = __builtin_amdgcn_mfma_f32_16x16x32_bf16(a[i], bfr[j], acc[i][j], 0, 0, 0);
        __syncthreads();
    }
    const int quad = (lane >> 4) * 4;
    const long pbase = ((long)ks * BB + b) * MM * CI;
    #pragma unroll
    for (int i = 0; i < 4; ++i) {
        #pragma unroll
        for (int j = 0; j < 4; ++j) {
            int mg = wm * 64 + i * 16 + quad;
            int cg = wn * 64 + j * 16 + fr;
            #pragma unroll
            for (int r = 0; r < 4; ++r)
                part[pbase + (long)(mg + r) * CI + cg] = __float2bfloat16(acc[i][j][r]);
        }
    }
}

__global__ __launch_bounds__(256) void k_mix(const bf16* __restrict__ part,
                                             const bf16* __restrict__ Wt,
                                             bf16* __restrict__ osT) {
    const int blk = blockIdx.x;
    const int m   = (blk & 7) * 32 + (blk >> 3);
    __shared__ bf16  Wl[CI][CO];
    __shared__ float xl[CI][36];
    const int t = threadIdx.x;
    const long wb = (long)m * CI * CO;
    #pragma unroll
    for (int i = 0; i < 8; ++i) {
        int ch = t + i * 256;
        int c = ch >> 4, og = (ch & 15) * 8;
        *(bf16x8*)&Wl[c][og] = *(const bf16x8*)&Wt[wb + (long)c * CO + og];
    }
    #pragma unroll
    for (int i = 0; i < 2; ++i) {
        int ch = t + i * 256;
        int b = ch >> 4, c8 = (ch & 15) * 8;
        float s[8] = {};
        #pragma unroll
        for (int ks = 0; ks < KS; ++ks) {
            bf16x8 v = *(const bf16x8*)&part[(((long)ks * BB + b) * MM + m) * CI + c8];
            #pragma unroll
            for (int j = 0; j < 8; ++j) s[j] += __bfloat162float(((const bf16*)&v)[j]);
        }
        #pragma unroll
        for (int j = 0; j < 8; ++j) xl[c8 + j][b] = s[j];
    }
    __syncthreads();
    const int o  = t & 127;
    const int bh = t >> 7;
    float acc[16] = {};
    for (int c = 0; c < CI; ++c) {
        float w = __bfloat162float(Wl[c][o]);
        #pragma unroll
        for (int j = 0; j < 16; ++j)
            acc[j] += xl[c][bh * 16 + j] * w;
    }
    #pragma unroll
    for (int j = 0; j < 16; ++j)
        osT[((long)(bh * 16 + j) * CO + o) * MM + m] = __float2bfloat16(acc[j]);
}

__global__ __launch_bounds__(256) void k_gemm3(const bf16* __restrict__ Un,
                                               const bf16* __restrict__ osT,
                                               float* __restrict__ out) {
    const int n0 = blockIdx.x * 128;
    const int b  = blockIdx.y;
    __shared__ __align__(16) bf16 As[128 * 32];
    __shared__ __align__(16) bf16 Bs[128 * 32];
    const int t    = threadIdx.x;
    const int lane = t & 63;
    const int wave = t >> 6;
    const int wm   = wave >> 1, wn = wave & 1;
    const int fr   = lane & 15;
    const int kg   = (lane >> 4) * 8;
    f32x4 acc[4][4] = {};
    const long bbase = (long)b * CO * MM;
    for (int kt = 0; kt < MM / 32; ++kt) {
        const int k0 = kt * 32;
        #pragma unroll
        for (int i = 0; i < 2; ++i) {
            int lin = t + i * 256;
            int r = lin >> 2, kk = (lin & 3) * 8;
            gl_lds16(&Un[(long)(n0 + r) * MM + k0 + kk], &As[lin * 8]);
            gl_lds16(&osT[bbase + (long)r * MM + k0 + kk], &Bs[lin * 8]);
        }
        __syncthreads();
        bf16x8 a[4], bfr[4];
        #pragma unroll
        for (int i = 0; i < 4; ++i)
            a[i] = *(const bf16x8*)&As[(wm * 64 + i * 16 + fr) * 32 + kg];
        #pragma unroll
        for (int j = 0; j < 4; ++j)
            bfr[j] = *(const bf16x8*)&Bs[(wn * 64 + j * 16 + fr) * 32 + kg];
        #pragma unroll
        for (int i = 0; i < 4; ++i)
            #pragma unroll
            for (int j = 0; j < 4; ++j)
                acc[i][j] = __builtin_amdgcn_mfma_f32_16x16x32_bf16(a[i], bfr[j], acc[i][j], 0, 0, 0);
        __syncthreads();
    }
    const int quad = (lane >> 4) * 4;
    #pragma unroll
    for (int i = 0; i < 4; ++i) {
        #pragma unroll
        for (int j = 0; j < 4; ++j) {
            int ng = n0 + wm * 64 + i * 16 + quad;
            int og = wn * 64 + j * 16 + fr;
            #pragma unroll
            for (int r = 0; r < 4; ++r)
                out[((long)b * NN + ng + r) * CO + og] = acc[i][j][r];
        }
    }
}

extern "C" void kernel_launch(void* const* d_in, const int* in_sizes, int n_in,
                              void* d_out, int out_size, void* d_ws, size_t ws_size,
                              hipStream_t stream) {
    const float* x  = (const float*)d_in[0];   // [32][4096][128]
    const float* U  = (const float*)d_in[1];   // [4096][256]
    const float* Wr = (const float*)d_in[2];   // [128][128][256]
    float* out = (float*)d_out;                // [32][4096][128]

    char* p = (char*)d_ws;
    bf16* part = (bf16*)p;  p += (size_t)KS * BB * MM * CI * 2;   // 16 MB
    bf16* Ut   = (bf16*)p;  p += (size_t)MM * NN * 2;             // 2 MB
    bf16* Un   = (bf16*)p;  p += (size_t)NN * MM * 2;             // 2 MB
    bf16* osT  = (bf16*)p;  p += (size_t)BB * CO * MM * 2;        // 2 MB
    bf16* Wt   = (bf16*)p;  p += (size_t)MM * CI * CO * 2;        // 8 MB

    const float* xa = x; const float* Ua = U; const float* Wa = Wr;
    float* outa = out;
    bf16 *parta = part, *Uta = Ut, *Una = Un, *osTa = osT, *Wta = Wt;
    void* args[] = {&xa, &Ua, &Wa, &outa, &parta, &Uta, &Una, &osTa, &Wta};

    hipError_t err = hipLaunchCooperativeKernel((const void*)k_all,
                                                dim3(512), dim3(256),
                                                args, 0, stream);
    if (err != hipSuccess) {
        // fallback: verified round-4 multi-kernel path
        k_cvtU  <<<dim3(NN / 64, MM / 64), 256, 0, stream>>>(U, Un, Ut);
        k_wt    <<<dim3(MM / 64, CO / 64, CI), 256, 0, stream>>>(Wr, Wt);
        k_gemm1f<<<dim3(KS, BB), 512, 0, stream>>>(Ut, x, part);
        k_mix   <<<dim3(256), 256, 0, stream>>>(part, Wt, osT);
        k_gemm3 <<<dim3(NN / 128, BB), 256, 0, stream>>>(Un, osT, out);
    }
}

// Round 6
// 182.870 us; speedup vs baseline: 3.1660x; 3.1660x over previous
//
#include <hip/hip_runtime.h>
#include <hip/hip_bf16.h>

// GraphFourierLayer: B=32, N=4096, C_IN=128, C_OUT=128, M=256
#define BB 32
#define NN 4096
#define CI 128
#define CO 128
#define MM 256
#define KS 8           // K-split factor for stage 1 (N=4096 -> 8 chunks of 512)

typedef __hip_bfloat16 bf16;
typedef __attribute__((ext_vector_type(8))) short bf16x8;
typedef __attribute__((ext_vector_type(4))) float f32x4;

__device__ inline void gl_lds16(const void* g, void* l) {
    __builtin_amdgcn_global_load_lds(
        (const __attribute__((address_space(1))) void*)g,
        (__attribute__((address_space(3))) void*)l, 16, 0, 0);
}

// ---------------------------------------------------------------------------
// Prep (merged): blocks 0..255 = cvtU (U -> Un, Ut), blocks 256..1279 = wt
// (W -> Wt). Bodies are the verified k_cvtU / k_wt verbatim; merging removes
// one launch boundary and lets the two preps run concurrently.
// ---------------------------------------------------------------------------
__global__ __launch_bounds__(256) void k_prep(const float* __restrict__ U,
                                              const float* __restrict__ W,
                                              bf16* __restrict__ Un,
                                              bf16* __restrict__ Ut,
                                              bf16* __restrict__ Wt) {
    const int blk = blockIdx.x;
    const int t = threadIdx.x;
    __shared__ float tile[64][65];
    if (blk < 256) {
        // ---- cvtU: U fp32 [N][M] -> Un bf16 [N][M], Ut bf16 [M][N] ----
        const int n0 = (blk & 63) * 64;
        const int m0 = (blk >> 6) * 64;
        #pragma unroll
        for (int i = 0; i < 16; ++i) {
            int lin = t + i * 256;
            int r = lin >> 6, c = lin & 63;
            float v = U[(n0 + r) * MM + m0 + c];
            tile[r][c] = v;
            Un[(n0 + r) * MM + m0 + c] = __float2bfloat16(v);
        }
        __syncthreads();
        #pragma unroll
        for (int pass = 0; pass < 2; ++pass) {
            int no = t & 7;                    // n-octet
            int m  = (t >> 3) + pass * 32;     // m-local
            bf16 tmp[8];
            #pragma unroll
            for (int j = 0; j < 8; ++j) tmp[j] = __float2bfloat16(tile[no * 8 + j][m]);
            *(bf16x8*)&Ut[(long)(m0 + m) * NN + n0 + no * 8] = *(bf16x8*)tmp;
        }
    } else {
        // ---- wt: W fp32 [C][O][M] -> Wt bf16 [M][C][O] ----
        const int q  = blk - 256;              // 0..1023
        const int c  = q >> 3;                 // 0..127
        const int m0 = (q & 3) * 64;
        const int o0 = ((q >> 2) & 1) * 64;
        #pragma unroll
        for (int pass = 0; pass < 4; ++pass) {
            int r  = (t >> 4) + pass * 16;     // o-local
            int m4 = (t & 15) * 4;             // m-local
            float4 v = *(const float4*)&W[((long)c * CO + o0 + r) * MM + m0 + m4];
            tile[r][m4 + 0] = v.x; tile[r][m4 + 1] = v.y;
            tile[r][m4 + 2] = v.z; tile[r][m4 + 3] = v.w;
        }
        __syncthreads();
        #pragma unroll
        for (int pass = 0; pass < 2; ++pass) {
            int oo = t & 7;                    // o-octet
            int m  = (t >> 3) + pass * 32;     // m-local
            bf16 tmp[8];
            #pragma unroll
            for (int j = 0; j < 8; ++j) tmp[j] = __float2bfloat16(tile[oo * 8 + j][m]);
            *(bf16x8*)&Wt[((long)(m0 + m) * CI + c) * CO + o0 + oo * 8] = *(bf16x8*)tmp;
        }
    }
}

// ---------------------------------------------------------------------------
// Stage 1 fused (MFMA, K-split, in-kernel x transpose+convert):
//   part[ks][b][m][c] = sum_n Ut[m][n] * x[b][n][c]
// mt-split 128x128 tile, 256 threads, 64 KB LDS -> 2 blocks/CU (vs 1 for the
// 256-row variant): two independent blocks overlap each other's barrier
// stalls. Body verified in round 5 (mega P1 passed). Block layout
// bx = ks + 8*mt + 16*b: the mt pair of one (ks,b) is 8 apart -> same XCD
// (round-robin %8), so the shared x tile is L2-local.
// ---------------------------------------------------------------------------
__global__ __launch_bounds__(256) void k_gemm1f(const bf16* __restrict__ Ut,
                                                const float* __restrict__ x,
                                                bf16* __restrict__ part) {
    const int bx = blockIdx.x;
    const int ks = bx & 7;
    const int mt = (bx >> 3) & 1;
    const int b  = bx >> 4;
    const int m0 = mt * 128;
    __shared__ __align__(16) bf16  As[2][128 * 32];   // 16 KB
    __shared__ __align__(16) bf16  Bs[2][128 * 32];   // 16 KB
    __shared__ __align__(16) float Xf[2][32 * 128];   // 32 KB
    const int t    = threadIdx.x;
    const int lane = t & 63;
    const int wave = t >> 6;
    const int wm   = wave >> 1, wn = wave & 1;        // 2 x 2 waves
    const int fr   = lane & 15;
    const int kg   = (lane >> 4) * 8;
    f32x4 acc[4][4] = {};
    const long xrow  = (long)b * NN;
    const int  kbase = ks * 512;

    auto STAGE = [&](int buf, int kt) {
        const int k0 = kbase + kt * 32;
        #pragma unroll
        for (int i = 0; i < 2; ++i) {
            int lin = t + i * 256;
            int r = lin >> 2, kk = (lin & 3) * 8;
            gl_lds16(&Ut[(long)(m0 + r) * NN + k0 + kk], &As[buf][lin * 8]);
        }
        #pragma unroll
        for (int i = 0; i < 4; ++i) {
            int lin = t + i * 256;
            int r = lin >> 5, c4 = (lin & 31) * 4;
            gl_lds16(&x[(xrow + k0 + r) * CI + c4], &Xf[buf][lin * 4]);
        }
    };

    STAGE(0, 0);
    __syncthreads();
    for (int kt = 0; kt < 16; ++kt) {
        const int cur = kt & 1;
        {   // transpose+convert Xf[cur] [32 n][128 c] -> Bs[cur] [128 c][32 n]
            const int c = t & 127;
            #pragma unroll
            for (int pass = 0; pass < 2; ++pass) {
                int no = (t >> 7) + pass * 2;          // 0..3
                bf16 tmp[8];
                #pragma unroll
                for (int j = 0; j < 8; ++j)
                    tmp[j] = __float2bfloat16(Xf[cur][(no * 8 + j) * 128 + c]);
                *(bf16x8*)&Bs[cur][c * 32 + no * 8] = *(bf16x8*)tmp;
            }
        }
        __syncthreads();                      // Bs[cur] visible; nothing outstanding
        if (kt + 1 < 16) STAGE(cur ^ 1, kt + 1);   // loads fly under MFMA phase
        bf16x8 a[4], bfr[4];
        #pragma unroll
        for (int i = 0; i < 4; ++i)
            a[i] = *(const bf16x8*)&As[cur][(wm * 64 + i * 16 + fr) * 32 + kg];
        #pragma unroll
        for (int j = 0; j < 4; ++j)
            bfr[j] = *(const bf16x8*)&Bs[cur][(wn * 64 + j * 16 + fr) * 32 + kg];
        #pragma unroll
        for (int i = 0; i < 4; ++i)
            #pragma unroll
            for (int j = 0; j < 4; ++j)
                acc[i][j] = __builtin_amdgcn_mfma_f32_16x16x32_bf16(a[i], bfr[j], acc[i][j], 0, 0, 0);
        __syncthreads();                      // drain loads + protect buffers
    }
    const int quad = (lane >> 4) * 4;
    const long pbase = ((long)ks * BB + b) * MM * CI;
    #pragma unroll
    for (int i = 0; i < 4; ++i) {
        #pragma unroll
        for (int j = 0; j < 4; ++j) {
            int mg = m0 + wm * 64 + i * 16 + quad;
            int cg = wn * 64 + j * 16 + fr;
            #pragma unroll
            for (int r = 0; r < 4; ++r)
                part[pbase + (long)(mg + r) * CI + cg] = __float2bfloat16(acc[i][j][r]);
        }
    }
}

// ---------------------------------------------------------------------------
// Stage 2: reduce K-split partials + per-mode channel mix -> osT[b][o][m] bf16
// One block per mode (full 128-o): part slice read ONCE. Verified R3/R4.
// ---------------------------------------------------------------------------
__global__ __launch_bounds__(256) void k_mix(const bf16* __restrict__ part,
                                             const bf16* __restrict__ Wt,
                                             bf16* __restrict__ osT) {
    const int blk = blockIdx.x;                 // 0..255
    const int m   = (blk & 7) * 32 + (blk >> 3); // XCD swizzle on mode
    __shared__ bf16  Wl[CI][CO];                // 32 KB, kept bf16
    __shared__ float xl[CI][36];                // 18 KB (+pad)
    const int t = threadIdx.x;
    const long wb = (long)m * CI * CO;
    #pragma unroll
    for (int i = 0; i < 8; ++i) {
        int ch = t + i * 256;
        int c = ch >> 4, og = (ch & 15) * 8;
        *(bf16x8*)&Wl[c][og] = *(const bf16x8*)&Wt[wb + (long)c * CO + og];
    }
    #pragma unroll
    for (int i = 0; i < 2; ++i) {
        int ch = t + i * 256;
        int b = ch >> 4, c8 = (ch & 15) * 8;
        float s[8] = {};
        #pragma unroll
        for (int ks = 0; ks < KS; ++ks) {
            bf16x8 v = *(const bf16x8*)&part[(((long)ks * BB + b) * MM + m) * CI + c8];
            #pragma unroll
            for (int j = 0; j < 8; ++j) s[j] += __bfloat162float(((const bf16*)&v)[j]);
        }
        #pragma unroll
        for (int j = 0; j < 8; ++j) xl[c8 + j][b] = s[j];
    }
    __syncthreads();
    const int o  = t & 127;
    const int bh = t >> 7;                      // 0..1 -> 16 b each
    float acc[16] = {};
    for (int c = 0; c < CI; ++c) {
        float w = __bfloat162float(Wl[c][o]);
        #pragma unroll
        for (int j = 0; j < 16; ++j)
            acc[j] += xl[c][bh * 16 + j] * w;
    }
    #pragma unroll
    for (int j = 0; j < 16; ++j)
        osT[((long)(bh * 16 + j) * CO + o) * MM + m] = __float2bfloat16(acc[j]);
}

// ---------------------------------------------------------------------------
// Stage 3 (MFMA): out[b][n][o] = sum_m Un[n][m] * osT[b][o][m]. K=256.
// Verified single-buffer syncthreads body (R3/R5). 1024 blocks = 4/CU.
// ---------------------------------------------------------------------------
__global__ __launch_bounds__(256) void k_gemm3(const bf16* __restrict__ Un,
                                               const bf16* __restrict__ osT,
                                               float* __restrict__ out) {
    const int n0 = blockIdx.x * 128;
    const int b  = blockIdx.y;
    __shared__ __align__(16) bf16 As[128 * 32];
    __shared__ __align__(16) bf16 Bs[128 * 32];
    const int t    = threadIdx.x;
    const int lane = t & 63;
    const int wave = t >> 6;
    const int wm   = wave >> 1, wn = wave & 1;
    const int fr   = lane & 15;
    const int kg   = (lane >> 4) * 8;
    f32x4 acc[4][4] = {};
    const long bbase = (long)b * CO * MM;
    for (int kt = 0; kt < MM / 32; ++kt) {
        const int k0 = kt * 32;
        #pragma unroll
        for (int i = 0; i < 2; ++i) {
            int lin = t + i * 256;
            int r = lin >> 2, kk = (lin & 3) * 8;
            gl_lds16(&Un[(long)(n0 + r) * MM + k0 + kk], &As[lin * 8]);
            gl_lds16(&osT[bbase + (long)r * MM + k0 + kk], &Bs[lin * 8]);
        }
        __syncthreads();
        bf16x8 a[4], bfr[4];
        #pragma unroll
        for (int i = 0; i < 4; ++i)
            a[i] = *(const bf16x8*)&As[(wm * 64 + i * 16 + fr) * 32 + kg];
        #pragma unroll
        for (int j = 0; j < 4; ++j)
            bfr[j] = *(const bf16x8*)&Bs[(wn * 64 + j * 16 + fr) * 32 + kg];
        #pragma unroll
        for (int i = 0; i < 4; ++i)
            #pragma unroll
            for (int j = 0; j < 4; ++j)
                acc[i][j] = __builtin_amdgcn_mfma_f32_16x16x32_bf16(a[i], bfr[j], acc[i][j], 0, 0, 0);
        __syncthreads();
    }
    const int quad = (lane >> 4) * 4;
    #pragma unroll
    for (int i = 0; i < 4; ++i) {
        #pragma unroll
        for (int j = 0; j < 4; ++j) {
            int ng = n0 + wm * 64 + i * 16 + quad;
            int og = wn * 64 + j * 16 + fr;
            #pragma unroll
            for (int r = 0; r < 4; ++r)
                out[((long)b * NN + ng + r) * CO + og] = acc[i][j][r];
        }
    }
}

extern "C" void kernel_launch(void* const* d_in, const int* in_sizes, int n_in,
                              void* d_out, int out_size, void* d_ws, size_t ws_size,
                              hipStream_t stream) {
    const float* x  = (const float*)d_in[0];   // [32][4096][128]
    const float* U  = (const float*)d_in[1];   // [4096][256]
    const float* Wr = (const float*)d_in[2];   // [128][128][256]
    float* out = (float*)d_out;                // [32][4096][128]

    char* p = (char*)d_ws;
    bf16* part = (bf16*)p;  p += (size_t)KS * BB * MM * CI * 2;   // 16 MB
    bf16* Ut   = (bf16*)p;  p += (size_t)MM * NN * 2;             // 2 MB
    bf16* Un   = (bf16*)p;  p += (size_t)NN * MM * 2;             // 2 MB
    bf16* osT  = (bf16*)p;  p += (size_t)BB * CO * MM * 2;        // 2 MB
    bf16* Wt   = (bf16*)p;  p += (size_t)MM * CI * CO * 2;        // 8 MB

    k_prep  <<<dim3(1280), 256, 0, stream>>>(U, Wr, Un, Ut, Wt);
    k_gemm1f<<<dim3(KS * 2 * BB), 256, 0, stream>>>(Ut, x, part);
    k_mix   <<<dim3(256), 256, 0, stream>>>(part, Wt, osT);
    k_gemm3 <<<dim3(NN / 128, BB), 256, 0, stream>>>(Un, osT, out);
}